// Round 14
// baseline (240.717 us; speedup 1.0000x reference)
//
#include <hip/hip_runtime.h>

// x[16,64,96,96] f32, dict[100,64,3,3] f32, coeff[256,3,3,3] f32, idx[256,3,3,3] i32
// out[16,256,96,96] f32
#define NB   16
#define CIN  64
#define HH   96
#define WW   96
#define DD   100
#define OO   256
#define NWG  (NB * HH)       // 1536 transpose blocks in prep
#define NCV  (NB * HH * 2)   // 3072 conv blocks: (b, h, w-half), 256 threads each
#define WPAD 50              // wp slots per row: w in [ws-1, ws+48]

typedef __attribute__((ext_vector_type(8))) short  bf16x8;
typedef __attribute__((ext_vector_type(4))) float  f32x4;

// XOR swizzle on the 16B-granule bits (4-6) within a 128B (= one wp) row
#define FSWZ(wp) ((((wp) ^ ((wp) >> 3)) & 7) << 4)

static __device__ __forceinline__ unsigned short f32_to_bf16(float f) {
    unsigned int u = __float_as_uint(f);
    u += 0x7FFFu + ((u >> 16) & 1u);   // RNE
    return (unsigned short)(u >> 16);
}

// ---- fused prep:
//  blocks [0,1536): x f32 NCHW -> bf16 NHWC (x2[b][h][w][c])
//  blocks [1536,1792): W_eff = scatter(coeff,idx) @ dict, MFMA B-fragment order:
//    halfword index = (kpos*32 + otile*2 + ks)*512 + lane*8 + e;  block 1536 also zeroes zbuf
__global__ __launch_bounds__(256) void prep_kernel(
    const float* __restrict__ x, const float* __restrict__ dict,
    const float* __restrict__ coeff, const int* __restrict__ idx,
    unsigned short* __restrict__ x2, unsigned short* __restrict__ weff2,
    unsigned short* __restrict__ zbuf)
{
    __shared__ unsigned short lds[CIN * 100];
    __shared__ float wrow[DD];
    const int blk = blockIdx.x, tid = threadIdx.x;

    if (blk < NWG) {
        const int b = blk / HH, h = blk % HH;
        for (int it = 0; it < 6; ++it) {
            int i = tid + it * 256;                  // 64*24 float4 units
            int c = i / 24, w4 = i % 24;
            float4 v = *reinterpret_cast<const float4*>(
                x + (((size_t)(b * CIN + c) * HH + h) * WW + w4 * 4));
            ushort4 u;
            u.x = f32_to_bf16(v.x); u.y = f32_to_bf16(v.y);
            u.z = f32_to_bf16(v.z); u.w = f32_to_bf16(v.w);
            *reinterpret_cast<ushort4*>(&lds[c * 100 + w4 * 4]) = u;
        }
        __syncthreads();
        for (int it = 0; it < 6; ++it) {
            int i = tid + it * 256;                  // 96*16 ushort4 units
            int w = i / 16, c = (i % 16) * 4;
            ushort4 u;
            u.x = lds[(c + 0) * 100 + w];
            u.y = lds[(c + 1) * 100 + w];
            u.z = lds[(c + 2) * 100 + w];
            u.w = lds[(c + 3) * 100 + w];
            *reinterpret_cast<ushort4*>(x2 + (((size_t)(b * HH + h) * WW + w) * CIN + c)) = u;
        }
    } else {
        const int o = blk - NWG;
        if (o == 0 && tid < 8) zbuf[tid] = 0;        // 16B zero source for pads
        if (tid < DD) wrow[tid] = 0.f;
        __syncthreads();
        if (tid == 0) {                              // deterministic serial scatter
            for (int s = 0; s < 27; ++s) wrow[idx[o * 27 + s]] += coeff[o * 27 + s];
        }
        __syncthreads();
        for (int j = tid; j < 576; j += 256) {       // j = kpos*64 + c
            int kpos = j >> 6, c = j & 63;
            float s = 0.f;
            for (int d = 0; d < DD; ++d)
                s += wrow[d] * dict[d * 576 + c * 9 + kpos];
            int otile = o >> 4, ks = c >> 5;
            int lane8 = (o & 15) | (((c >> 3) & 3) << 4);
            weff2[((size_t)(kpos * 32 + otile * 2 + ks)) * 512 + lane8 * 8 + (c & 7)]
                = f32_to_bf16(s);
        }
    }
}

// ---- conv: block = (b, h, w-half of 48); 256 threads = 4 waves = 4 o-quarters.
// R13 + A-fragment ping-pong: step s+1's 3 ds_read_b128 issue BEFORE step s's
// MFMAs (indices fold to constants after full unroll), so LDS latency hides
// under the MFMA cluster. setprio(1) around MFMAs (4 independent blocks/CU
// give the CU scheduler real role diversity to arbitrate).
__global__ __launch_bounds__(256, 4) void conv_kernel(
    const unsigned short* __restrict__ x2,     // [16][96][96][64] bf16 NHWC
    const unsigned short* __restrict__ weff2,  // fragment-ordered, 288KB (L2-resident)
    const unsigned short* __restrict__ zbuf,   // 16B of zeros
    float* __restrict__ out)                   // [16][256][96][96] f32
{
    __shared__ unsigned short xs[3 * WPAD * 64]; // 3 rows x 50 wp x 64c, 19200 B

    const int wg  = blockIdx.x;
    const int swz = (wg & 7) * (NCV / 8) + (wg >> 3);  // XCD-bijective (3072%8==0)
    const int b = swz / 192, rem = swz % 192;
    const int h = rem >> 1, ws = (rem & 1) * 48;
    const int tid = threadIdx.x;
    const int lane = tid & 63, wn = tid >> 6;          // wn = o-quarter
    const int l15 = lane & 15;

    char* xsb = reinterpret_cast<char*>(xs);
    const char* x2b = reinterpret_cast<const char*>(x2) + (size_t)b * HH * WW * 128;
    const char* zbp = reinterpret_cast<const char*>(zbuf);

    // ---- B-fragment prologue: banks for steps 0..3 (fly under staging) ----
    const unsigned short* wbase = weff2 + (size_t)(wn * 8) * 512 + lane * 8;
    bf16x8 bfr[4][4];
#pragma unroll
    for (int s = 0; s < 4; ++s)
#pragma unroll
        for (int n = 0; n < 4; ++n)
            bfr[s][n] = *reinterpret_cast<const bf16x8*>(
                wbase + (((s >> 1) * 32) + n * 2 + (s & 1)) * 512);

    // ---- stage rows h-1..h+1, wp in [0,50) (global w = ws-1+wp) ----
#pragma unroll
    for (int it = 0; it < 5; ++it) {
        int chunk = tid + it * 256;            // 3*50*8 = 1200 chunks of 16B
        if (chunk < 1200) {
            int r = chunk / 400, rem2 = chunk % 400;
            int wp = rem2 >> 3, gb = (rem2 & 7) << 4;
            int hp = h - 1 + r, w = ws - 1 + wp;
            const char* src = (w >= 0 && w < WW && hp >= 0 && hp < HH)
                ? x2b + ((size_t)(hp * WW + w) * 128 + (gb ^ FSWZ(wp)))
                : zbp;
            __builtin_amdgcn_global_load_lds(
                (const __attribute__((address_space(1))) void*)src,
                (__attribute__((address_space(3))) void*)(xsb + chunk * 16),
                16, 0, 0);
        }
    }

    f32x4 acc[3][4];
#pragma unroll
    for (int m = 0; m < 3; ++m)
#pragma unroll
        for (int n = 0; n < 4; ++n)
            acc[m][n] = (f32x4){0.f, 0.f, 0.f, 0.f};

    __syncthreads();                           // xs staged (only barrier)

    // ---- A ping-pong: preload step 0, then loop with 1-step lookahead ----
    bf16x8 ax[2][3];
    {
        const int cb0 = ((lane >> 4) * 8) * 2;           // step 0: ks=0, dw=0, kh=0
#pragma unroll
        for (int m = 0; m < 3; ++m) {
            int wpos = m * 16 + l15;
            ax[0][m] = *reinterpret_cast<const bf16x8*>(
                xsb + wpos * 128 + (cb0 ^ FSWZ(wpos)));
        }
    }

    // ---- 18 half-steps: s = (kpos=s>>1, ks=s&1); bank = s&3, B-prefetch +4 ----
#pragma unroll
    for (int s = 0; s < 18; ++s) {
        if (s < 17) {                          // prefetch A for step s+1
            const int s1 = s + 1;
            const int kpos1 = s1 >> 1, ks1 = s1 & 1;
            const int kh1 = kpos1 / 3, dw1 = kpos1 % 3;
            const int cb1 = (ks1 * 32 + (lane >> 4) * 8) * 2;
#pragma unroll
            for (int m = 0; m < 3; ++m) {
                int wpos = m * 16 + l15 + dw1;
                ax[s1 & 1][m] = *reinterpret_cast<const bf16x8*>(
                    xsb + kh1 * 6400 + wpos * 128 + (cb1 ^ FSWZ(wpos)));
            }
        }
        __builtin_amdgcn_s_setprio(1);
#pragma unroll
        for (int m = 0; m < 3; ++m)
#pragma unroll
            for (int n = 0; n < 4; ++n)
                acc[m][n] = __builtin_amdgcn_mfma_f32_16x16x32_bf16(
                    ax[s & 1][m], bfr[s & 3][n], acc[m][n], 0, 0, 0);
        __builtin_amdgcn_s_setprio(0);
        if (s < 14) {                          // reload this bank with step s+4
            const int s4 = s + 4;
            const int off = (s4 >> 1) * 32 + (s4 & 1);
#pragma unroll
            for (int n = 0; n < 4; ++n)
                bfr[s & 3][n] = *reinterpret_cast<const bf16x8*>(
                    wbase + (off + n * 2) * 512);
        }
    }

    // ---- epilogue: plain float4 stores ----
#pragma unroll
    for (int m = 0; m < 3; ++m)
#pragma unroll
        for (int n = 0; n < 4; ++n) {
            int o = wn * 64 + n * 16 + l15;
            int w = ws + m * 16 + (lane >> 4) * 4;
            *reinterpret_cast<f32x4*>(
                out + (((size_t)(b * OO + o) * HH + h) * WW + w)) = acc[m][n];
        }
}

extern "C" void kernel_launch(void* const* d_in, const int* in_sizes, int n_in,
                              void* d_out, int out_size, void* d_ws, size_t ws_size,
                              hipStream_t stream) {
    const float* x     = (const float*)d_in[0];
    const float* dict  = (const float*)d_in[1];
    const float* coeff = (const float*)d_in[2];
    const int*   idx   = (const int*)d_in[3];
    float* out = (float*)d_out;

    char* ws = (char*)d_ws;
    unsigned short* weff2 = (unsigned short*)ws;               // 294912 B
    unsigned short* zbuf  = (unsigned short*)(ws + 294912);    // 16 B zeros
    unsigned short* x2    = (unsigned short*)(ws + 1048576);   // 18874368 B

    prep_kernel<<<NWG + OO, 256, 0, stream>>>(x, dict, coeff, idx, x2, weff2, zbuf);
    conv_kernel<<<NCV, 256, 0, stream>>>(x2, weff2, zbuf, out);
}

// Round 15
// 79.542 us; speedup vs baseline: 3.0263x; 3.0263x over previous
//
#include <hip/hip_runtime.h>

// x[16,64,96,96] f32, dict[100,64,3,3] f32, coeff[256,3,3,3] f32, idx[256,3,3,3] i32
// out[16,256,96,96] f32
#define NB   16
#define CIN  64
#define HH   96
#define WW   96
#define DD   100
#define OO   256
#define NWG  (NB * HH)       // 1536 transpose blocks in prep
#define NCV  (NB * HH * 2)   // 3072 conv blocks: (b, h, w-half), 256 threads each
#define WPAD 50              // wp slots per row: w in [ws-1, ws+48]

typedef __attribute__((ext_vector_type(8))) short  bf16x8;
typedef __attribute__((ext_vector_type(4))) float  f32x4;

// XOR swizzle on the 16B-granule bits (4-6) within a 128B (= one wp) row
#define FSWZ(wp) ((((wp) ^ ((wp) >> 3)) & 7) << 4)

static __device__ __forceinline__ unsigned short f32_to_bf16(float f) {
    unsigned int u = __float_as_uint(f);
    u += 0x7FFFu + ((u >> 16) & 1u);   // RNE
    return (unsigned short)(u >> 16);
}

// ---- fused prep:
//  blocks [0,1536): x f32 NCHW -> bf16 NHWC (x2[b][h][w][c])
//  blocks [1536,1792): W_eff = scatter(coeff,idx) @ dict, MFMA B-fragment order:
//    halfword index = (kpos*32 + otile*2 + ks)*512 + lane*8 + e;  block 1536 also zeroes zbuf
__global__ __launch_bounds__(256) void prep_kernel(
    const float* __restrict__ x, const float* __restrict__ dict,
    const float* __restrict__ coeff, const int* __restrict__ idx,
    unsigned short* __restrict__ x2, unsigned short* __restrict__ weff2,
    unsigned short* __restrict__ zbuf)
{
    __shared__ unsigned short lds[CIN * 100];
    __shared__ float wrow[DD];
    const int blk = blockIdx.x, tid = threadIdx.x;

    if (blk < NWG) {
        const int b = blk / HH, h = blk % HH;
        for (int it = 0; it < 6; ++it) {
            int i = tid + it * 256;                  // 64*24 float4 units
            int c = i / 24, w4 = i % 24;
            float4 v = *reinterpret_cast<const float4*>(
                x + (((size_t)(b * CIN + c) * HH + h) * WW + w4 * 4));
            ushort4 u;
            u.x = f32_to_bf16(v.x); u.y = f32_to_bf16(v.y);
            u.z = f32_to_bf16(v.z); u.w = f32_to_bf16(v.w);
            *reinterpret_cast<ushort4*>(&lds[c * 100 + w4 * 4]) = u;
        }
        __syncthreads();
        for (int it = 0; it < 6; ++it) {
            int i = tid + it * 256;                  // 96*16 ushort4 units
            int w = i / 16, c = (i % 16) * 4;
            ushort4 u;
            u.x = lds[(c + 0) * 100 + w];
            u.y = lds[(c + 1) * 100 + w];
            u.z = lds[(c + 2) * 100 + w];
            u.w = lds[(c + 3) * 100 + w];
            *reinterpret_cast<ushort4*>(x2 + (((size_t)(b * HH + h) * WW + w) * CIN + c)) = u;
        }
    } else {
        const int o = blk - NWG;
        if (o == 0 && tid < 8) zbuf[tid] = 0;        // 16B zero source for pads
        if (tid < DD) wrow[tid] = 0.f;
        __syncthreads();
        if (tid == 0) {                              // deterministic serial scatter
            for (int s = 0; s < 27; ++s) wrow[idx[o * 27 + s]] += coeff[o * 27 + s];
        }
        __syncthreads();
        for (int j = tid; j < 576; j += 256) {       // j = kpos*64 + c
            int kpos = j >> 6, c = j & 63;
            float s = 0.f;
            for (int d = 0; d < DD; ++d)
                s += wrow[d] * dict[d * 576 + c * 9 + kpos];
            int otile = o >> 4, ks = c >> 5;
            int lane8 = (o & 15) | (((c >> 3) & 3) << 4);
            weff2[((size_t)(kpos * 32 + otile * 2 + ks)) * 512 + lane8 * 8 + (c & 7)]
                = f32_to_bf16(s);
        }
    }
}

// ---- conv: block = (b, h, w-half of 48); 256 threads = 4 waves = 4 o-quarters.
// R14 schedule (A ping-pong + depth-4 B banks, static unroll) with the register
// cap raised: __launch_bounds__(256, 3) -> ~170 VGPR budget, fits acc 48 +
// bfr 64 + ax 24 + addressing without spill at 3 blocks/CU (12 waves).
// Trades occupancy for in-wave ILP: each step's LDS latency hides under the
// previous step's MFMA cluster.
__global__ __launch_bounds__(256, 3) void conv_kernel(
    const unsigned short* __restrict__ x2,     // [16][96][96][64] bf16 NHWC
    const unsigned short* __restrict__ weff2,  // fragment-ordered, 288KB (L2-resident)
    const unsigned short* __restrict__ zbuf,   // 16B of zeros
    float* __restrict__ out)                   // [16][256][96][96] f32
{
    __shared__ unsigned short xs[3 * WPAD * 64]; // 3 rows x 50 wp x 64c, 19200 B

    const int wg  = blockIdx.x;
    const int swz = (wg & 7) * (NCV / 8) + (wg >> 3);  // XCD-bijective (3072%8==0)
    const int b = swz / 192, rem = swz % 192;
    const int h = rem >> 1, ws = (rem & 1) * 48;
    const int tid = threadIdx.x;
    const int lane = tid & 63, wn = tid >> 6;          // wn = o-quarter
    const int l15 = lane & 15;

    char* xsb = reinterpret_cast<char*>(xs);
    const char* x2b = reinterpret_cast<const char*>(x2) + (size_t)b * HH * WW * 128;
    const char* zbp = reinterpret_cast<const char*>(zbuf);

    // ---- B-fragment prologue: banks for steps 0..3 (fly under staging) ----
    const unsigned short* wbase = weff2 + (size_t)(wn * 8) * 512 + lane * 8;
    bf16x8 bfr[4][4];
#pragma unroll
    for (int s = 0; s < 4; ++s)
#pragma unroll
        for (int n = 0; n < 4; ++n)
            bfr[s][n] = *reinterpret_cast<const bf16x8*>(
                wbase + (((s >> 1) * 32) + n * 2 + (s & 1)) * 512);

    // ---- stage rows h-1..h+1, wp in [0,50) (global w = ws-1+wp) ----
#pragma unroll
    for (int it = 0; it < 5; ++it) {
        int chunk = tid + it * 256;            // 3*50*8 = 1200 chunks of 16B
        if (chunk < 1200) {
            int r = chunk / 400, rem2 = chunk % 400;
            int wp = rem2 >> 3, gb = (rem2 & 7) << 4;
            int hp = h - 1 + r, w = ws - 1 + wp;
            const char* src = (w >= 0 && w < WW && hp >= 0 && hp < HH)
                ? x2b + ((size_t)(hp * WW + w) * 128 + (gb ^ FSWZ(wp)))
                : zbp;
            __builtin_amdgcn_global_load_lds(
                (const __attribute__((address_space(1))) void*)src,
                (__attribute__((address_space(3))) void*)(xsb + chunk * 16),
                16, 0, 0);
        }
    }

    f32x4 acc[3][4];
#pragma unroll
    for (int m = 0; m < 3; ++m)
#pragma unroll
        for (int n = 0; n < 4; ++n)
            acc[m][n] = (f32x4){0.f, 0.f, 0.f, 0.f};

    __syncthreads();                           // xs staged (only barrier)

    // ---- A ping-pong: preload step 0, then loop with 1-step lookahead ----
    bf16x8 ax[2][3];
    {
        const int cb0 = ((lane >> 4) * 8) * 2;           // step 0: ks=0, dw=0, kh=0
#pragma unroll
        for (int m = 0; m < 3; ++m) {
            int wpos = m * 16 + l15;
            ax[0][m] = *reinterpret_cast<const bf16x8*>(
                xsb + wpos * 128 + (cb0 ^ FSWZ(wpos)));
        }
    }

    // ---- 18 half-steps: s = (kpos=s>>1, ks=s&1); bank = s&3, B-prefetch +4 ----
#pragma unroll
    for (int s = 0; s < 18; ++s) {
        if (s < 17) {                          // prefetch A for step s+1
            const int s1 = s + 1;
            const int kpos1 = s1 >> 1, ks1 = s1 & 1;
            const int kh1 = kpos1 / 3, dw1 = kpos1 % 3;
            const int cb1 = (ks1 * 32 + (lane >> 4) * 8) * 2;
#pragma unroll
            for (int m = 0; m < 3; ++m) {
                int wpos = m * 16 + l15 + dw1;
                ax[s1 & 1][m] = *reinterpret_cast<const bf16x8*>(
                    xsb + kh1 * 6400 + wpos * 128 + (cb1 ^ FSWZ(wpos)));
            }
        }
        __builtin_amdgcn_s_setprio(1);
#pragma unroll
        for (int m = 0; m < 3; ++m)
#pragma unroll
            for (int n = 0; n < 4; ++n)
                acc[m][n] = __builtin_amdgcn_mfma_f32_16x16x32_bf16(
                    ax[s & 1][m], bfr[s & 3][n], acc[m][n], 0, 0, 0);
        __builtin_amdgcn_s_setprio(0);
        if (s < 14) {                          // reload this bank with step s+4
            const int s4 = s + 4;
            const int off = (s4 >> 1) * 32 + (s4 & 1);
#pragma unroll
            for (int n = 0; n < 4; ++n)
                bfr[s & 3][n] = *reinterpret_cast<const bf16x8*>(
                    wbase + (off + n * 2) * 512);
        }
    }

    // ---- epilogue: plain float4 stores ----
#pragma unroll
    for (int m = 0; m < 3; ++m)
#pragma unroll
        for (int n = 0; n < 4; ++n) {
            int o = wn * 64 + n * 16 + l15;
            int w = ws + m * 16 + (lane >> 4) * 4;
            *reinterpret_cast<f32x4*>(
                out + (((size_t)(b * OO + o) * HH + h) * WW + w)) = acc[m][n];
        }
}

extern "C" void kernel_launch(void* const* d_in, const int* in_sizes, int n_in,
                              void* d_out, int out_size, void* d_ws, size_t ws_size,
                              hipStream_t stream) {
    const float* x     = (const float*)d_in[0];
    const float* dict  = (const float*)d_in[1];
    const float* coeff = (const float*)d_in[2];
    const int*   idx   = (const int*)d_in[3];
    float* out = (float*)d_out;

    char* ws = (char*)d_ws;
    unsigned short* weff2 = (unsigned short*)ws;               // 294912 B
    unsigned short* zbuf  = (unsigned short*)(ws + 294912);    // 16 B zeros
    unsigned short* x2    = (unsigned short*)(ws + 1048576);   // 18874368 B

    prep_kernel<<<NWG + OO, 256, 0, stream>>>(x, dict, coeff, idx, x2, weff2, zbuf);
    conv_kernel<<<NCV, 256, 0, stream>>>(x2, weff2, zbuf, out);
}

// Round 16
// 69.519 us; speedup vs baseline: 3.4626x; 1.1442x over previous
//
#include <hip/hip_runtime.h>

// x[16,64,96,96] f32, dict[100,64,3,3] f32, coeff[256,3,3,3] f32, idx[256,3,3,3] i32
// out[16,256,96,96] f32
#define NB   16
#define CIN  64
#define HH   96
#define WW   96
#define DD   100
#define OO   256
#define NWG  (NB * HH)       // 1536 transpose blocks in prep
#define NCV  3072            // conv blocks: b16 x hpair48 x whalf2 x ohalf2
#define WPAD 50              // wp slots per row: w in [ws-1, ws+48]

typedef __attribute__((ext_vector_type(8))) short  bf16x8;
typedef __attribute__((ext_vector_type(4))) float  f32x4;

// XOR swizzle on the 16B-granule bits (4-6) within a 128B (= one wp) row
#define FSWZ(wp) ((((wp) ^ ((wp) >> 3)) & 7) << 4)

static __device__ __forceinline__ unsigned short f32_to_bf16(float f) {
    unsigned int u = __float_as_uint(f);
    u += 0x7FFFu + ((u >> 16) & 1u);   // RNE
    return (unsigned short)(u >> 16);
}

// ---- fused prep:
//  blocks [0,1536): x f32 NCHW -> bf16 NHWC (x2[b][h][w][c])
//  blocks [1536,1792): W_eff = scatter(coeff,idx) @ dict, MFMA B-fragment order:
//    halfword index = (kpos*32 + otile*2 + ks)*512 + lane*8 + e;  block 1536 also zeroes zbuf
__global__ __launch_bounds__(256) void prep_kernel(
    const float* __restrict__ x, const float* __restrict__ dict,
    const float* __restrict__ coeff, const int* __restrict__ idx,
    unsigned short* __restrict__ x2, unsigned short* __restrict__ weff2,
    unsigned short* __restrict__ zbuf)
{
    __shared__ unsigned short lds[CIN * 100];
    __shared__ float wrow[DD];
    const int blk = blockIdx.x, tid = threadIdx.x;

    if (blk < NWG) {
        const int b = blk / HH, h = blk % HH;
        for (int it = 0; it < 6; ++it) {
            int i = tid + it * 256;                  // 64*24 float4 units
            int c = i / 24, w4 = i % 24;
            float4 v = *reinterpret_cast<const float4*>(
                x + (((size_t)(b * CIN + c) * HH + h) * WW + w4 * 4));
            ushort4 u;
            u.x = f32_to_bf16(v.x); u.y = f32_to_bf16(v.y);
            u.z = f32_to_bf16(v.z); u.w = f32_to_bf16(v.w);
            *reinterpret_cast<ushort4*>(&lds[c * 100 + w4 * 4]) = u;
        }
        __syncthreads();
        for (int it = 0; it < 6; ++it) {
            int i = tid + it * 256;                  // 96*16 ushort4 units
            int w = i / 16, c = (i % 16) * 4;
            ushort4 u;
            u.x = lds[(c + 0) * 100 + w];
            u.y = lds[(c + 1) * 100 + w];
            u.z = lds[(c + 2) * 100 + w];
            u.w = lds[(c + 3) * 100 + w];
            *reinterpret_cast<ushort4*>(x2 + (((size_t)(b * HH + h) * WW + w) * CIN + c)) = u;
        }
    } else {
        const int o = blk - NWG;
        if (o == 0 && tid < 8) zbuf[tid] = 0;        // 16B zero source for pads
        if (tid < DD) wrow[tid] = 0.f;
        __syncthreads();
        if (tid == 0) {                              // deterministic serial scatter
            for (int s = 0; s < 27; ++s) wrow[idx[o * 27 + s]] += coeff[o * 27 + s];
        }
        __syncthreads();
        for (int j = tid; j < 576; j += 256) {       // j = kpos*64 + c
            int kpos = j >> 6, c = j & 63;
            float s = 0.f;
            for (int d = 0; d < DD; ++d)
                s += wrow[d] * dict[d * 576 + c * 9 + kpos];
            int otile = o >> 4, ks = c >> 5;
            int lane8 = (o & 15) | (((c >> 3) & 3) << 4);
            weff2[((size_t)(kpos * 32 + otile * 2 + ks)) * 512 + lane8 * 8 + (c & 7)]
                = f32_to_bf16(s);
        }
    }
}

// ---- conv: block = (b, row-pair h0..h0+1, w-half 48, o-half 128).
// 256 threads = 4 waves, each n=2 o-tiles; per wave q=2 x m=3 x n=2 = 12 MFMA/step.
// q=2 cuts staging/output-row 3->2 and halves B-L2/output. A ping-pong (6 reads
// ahead), depth-4 B banks. Regs ~155 at __launch_bounds__(256,3) (~170 cap).
__global__ __launch_bounds__(256, 3) void conv_kernel(
    const unsigned short* __restrict__ x2,     // [16][96][96][64] bf16 NHWC
    const unsigned short* __restrict__ weff2,  // fragment-ordered, 288KB (L2-resident)
    const unsigned short* __restrict__ zbuf,   // 16B of zeros
    float* __restrict__ out)                   // [16][256][96][96] f32
{
    __shared__ unsigned short xs[4 * WPAD * 64]; // 4 rows x 50 wp x 64c, 25600 B

    const int wg  = blockIdx.x;
    const int swz = (wg & 7) * (NCV / 8) + (wg >> 3);  // XCD-bijective (3072%8==0)
    const int b = swz / 192, rem = swz % 192;
    const int hp = rem >> 2, wh = (rem >> 1) & 1, oh = rem & 1;  // oh fastest: L2 row sharing
    const int h0 = hp * 2, ws = wh * 48;
    const int tid = threadIdx.x;
    const int lane = tid & 63, wn = tid >> 6;          // wn = o-quarter of this o-half
    const int l15 = lane & 15;

    char* xsb = reinterpret_cast<char*>(xs);
    const char* x2b = reinterpret_cast<const char*>(x2) + (size_t)b * HH * WW * 128;
    const char* zbp = reinterpret_cast<const char*>(zbuf);

    // ---- B-fragment prologue: banks for steps 0..3 (fly under staging) ----
    // otile(n) = oh*8 + wn*2 + n; frag = kpos*32 + otile*2 + ks
    const unsigned short* wbase = weff2 + (size_t)((oh * 8 + wn * 2) * 2) * 512 + lane * 8;
    bf16x8 bfr[4][2];
#pragma unroll
    for (int s = 0; s < 4; ++s) {
        const int off = (s >> 1) * 32 + (s & 1);
#pragma unroll
        for (int n = 0; n < 2; ++n)
            bfr[s][n] = *reinterpret_cast<const bf16x8*>(wbase + (off + n * 2) * 512);
    }

    // ---- stage rows h0-1..h0+2, wp in [0,50) (global w = ws-1+wp) ----
#pragma unroll
    for (int it = 0; it < 7; ++it) {
        int chunk = tid + it * 256;            // 4*50*8 = 1600 chunks of 16B
        if (chunk < 1600) {
            int r = chunk / 400, rem2 = chunk % 400;
            int wp = rem2 >> 3, gb = (rem2 & 7) << 4;
            int hx = h0 - 1 + r, w = ws - 1 + wp;
            const char* src = (w >= 0 && w < WW && hx >= 0 && hx < HH)
                ? x2b + ((size_t)(hx * WW + w) * 128 + (gb ^ FSWZ(wp)))
                : zbp;
            __builtin_amdgcn_global_load_lds(
                (const __attribute__((address_space(1))) void*)src,
                (__attribute__((address_space(3))) void*)(xsb + chunk * 16),
                16, 0, 0);
        }
    }

    f32x4 acc[2][3][2];
#pragma unroll
    for (int q = 0; q < 2; ++q)
#pragma unroll
        for (int m = 0; m < 3; ++m)
#pragma unroll
            for (int n = 0; n < 2; ++n)
                acc[q][m][n] = (f32x4){0.f, 0.f, 0.f, 0.f};

    __syncthreads();                           // xs staged (only barrier)

    // ---- A ping-pong: preload step 0 (kh=0, dw=0, ks=0) for both rows ----
    bf16x8 ax[2][2][3];
    {
        const int cb0 = ((lane >> 4) * 8) * 2;
#pragma unroll
        for (int q = 0; q < 2; ++q)
#pragma unroll
            for (int m = 0; m < 3; ++m) {
                int wpos = m * 16 + l15;
                ax[0][q][m] = *reinterpret_cast<const bf16x8*>(
                    xsb + q * 6400 + wpos * 128 + (cb0 ^ FSWZ(wpos)));
            }
    }

    // ---- 18 half-steps: s = (kpos=s>>1, ks=s&1); bank = s&3, B-prefetch +4 ----
#pragma unroll
    for (int s = 0; s < 18; ++s) {
        if (s < 17) {                          // prefetch A for step s+1 (both rows)
            const int s1 = s + 1;
            const int kpos1 = s1 >> 1, ks1 = s1 & 1;
            const int kh1 = kpos1 / 3, dw1 = kpos1 % 3;
            const int cb1 = (ks1 * 32 + (lane >> 4) * 8) * 2;
#pragma unroll
            for (int q = 0; q < 2; ++q)
#pragma unroll
                for (int m = 0; m < 3; ++m) {
                    int wpos = m * 16 + l15 + dw1;
                    ax[s1 & 1][q][m] = *reinterpret_cast<const bf16x8*>(
                        xsb + (kh1 + q) * 6400 + wpos * 128 + (cb1 ^ FSWZ(wpos)));
                }
        }
        __builtin_amdgcn_s_setprio(1);
#pragma unroll
        for (int q = 0; q < 2; ++q)
#pragma unroll
            for (int m = 0; m < 3; ++m)
#pragma unroll
                for (int n = 0; n < 2; ++n)
                    acc[q][m][n] = __builtin_amdgcn_mfma_f32_16x16x32_bf16(
                        ax[s & 1][q][m], bfr[s & 3][n], acc[q][m][n], 0, 0, 0);
        __builtin_amdgcn_s_setprio(0);
        if (s < 14) {                          // reload this bank with step s+4
            const int s4 = s + 4;
            const int off = (s4 >> 1) * 32 + (s4 & 1);
#pragma unroll
            for (int n = 0; n < 2; ++n)
                bfr[s & 3][n] = *reinterpret_cast<const bf16x8*>(
                    wbase + (off + n * 2) * 512);
        }
    }

    // ---- epilogue: plain float4 stores ----
#pragma unroll
    for (int q = 0; q < 2; ++q)
#pragma unroll
        for (int m = 0; m < 3; ++m)
#pragma unroll
            for (int n = 0; n < 2; ++n) {
                int o = oh * 128 + wn * 32 + n * 16 + l15;
                int w = ws + m * 16 + (lane >> 4) * 4;
                *reinterpret_cast<f32x4*>(
                    out + (((size_t)(b * OO + o) * HH + h0 + q) * WW + w))
                    = acc[q][m][n];
            }
}

extern "C" void kernel_launch(void* const* d_in, const int* in_sizes, int n_in,
                              void* d_out, int out_size, void* d_ws, size_t ws_size,
                              hipStream_t stream) {
    const float* x     = (const float*)d_in[0];
    const float* dict  = (const float*)d_in[1];
    const float* coeff = (const float*)d_in[2];
    const int*   idx   = (const int*)d_in[3];
    float* out = (float*)d_out;

    char* ws = (char*)d_ws;
    unsigned short* weff2 = (unsigned short*)ws;               // 294912 B
    unsigned short* zbuf  = (unsigned short*)(ws + 294912);    // 16 B zeros
    unsigned short* x2    = (unsigned short*)(ws + 1048576);   // 18874368 B

    prep_kernel<<<NWG + OO, 256, 0, stream>>>(x, dict, coeff, idx, x2, weff2, zbuf);
    conv_kernel<<<NCV, 256, 0, stream>>>(x2, weff2, zbuf, out);
}

// Round 17
// 68.679 us; speedup vs baseline: 3.5050x; 1.0122x over previous
//
#include <hip/hip_runtime.h>

// x[16,64,96,96] f32, dict[100,64,3,3] f32, coeff[256,3,3,3] f32, idx[256,3,3,3] i32
// out[16,256,96,96] f32
#define NB   16
#define CIN  64
#define HH   96
#define WW   96
#define DD   100
#define OO   256
#define NWG  (NB * HH)       // 1536 transpose blocks in prep
#define NCV  1536            // conv blocks: b16 x hpair48 x whalf2 (all 256 o per block)
#define WPAD 50              // wp slots per row: w in [ws-1, ws+48]

typedef __attribute__((ext_vector_type(8))) short  bf16x8;
typedef __attribute__((ext_vector_type(4))) float  f32x4;

// XOR swizzle on the 16B-granule bits (4-6) within a 128B (= one wp) row
#define FSWZ(wp) ((((wp) ^ ((wp) >> 3)) & 7) << 4)

static __device__ __forceinline__ unsigned short f32_to_bf16(float f) {
    unsigned int u = __float_as_uint(f);
    u += 0x7FFFu + ((u >> 16) & 1u);   // RNE
    return (unsigned short)(u >> 16);
}

// ---- fused prep:
//  blocks [0,1536): x f32 NCHW -> bf16 NHWC (x2[b][h][w][c])
//  blocks [1536,1792): W_eff = scatter(coeff,idx) @ dict, MFMA B-fragment order:
//    halfword index = (kpos*32 + otile*2 + ks)*512 + lane*8 + e;  block 1536 also zeroes zbuf
__global__ __launch_bounds__(256) void prep_kernel(
    const float* __restrict__ x, const float* __restrict__ dict,
    const float* __restrict__ coeff, const int* __restrict__ idx,
    unsigned short* __restrict__ x2, unsigned short* __restrict__ weff2,
    unsigned short* __restrict__ zbuf)
{
    __shared__ unsigned short lds[CIN * 100];
    __shared__ float wrow[DD];
    const int blk = blockIdx.x, tid = threadIdx.x;

    if (blk < NWG) {
        const int b = blk / HH, h = blk % HH;
        for (int it = 0; it < 6; ++it) {
            int i = tid + it * 256;                  // 64*24 float4 units
            int c = i / 24, w4 = i % 24;
            float4 v = *reinterpret_cast<const float4*>(
                x + (((size_t)(b * CIN + c) * HH + h) * WW + w4 * 4));
            ushort4 u;
            u.x = f32_to_bf16(v.x); u.y = f32_to_bf16(v.y);
            u.z = f32_to_bf16(v.z); u.w = f32_to_bf16(v.w);
            *reinterpret_cast<ushort4*>(&lds[c * 100 + w4 * 4]) = u;
        }
        __syncthreads();
        for (int it = 0; it < 6; ++it) {
            int i = tid + it * 256;                  // 96*16 ushort4 units
            int w = i / 16, c = (i % 16) * 4;
            ushort4 u;
            u.x = lds[(c + 0) * 100 + w];
            u.y = lds[(c + 1) * 100 + w];
            u.z = lds[(c + 2) * 100 + w];
            u.w = lds[(c + 3) * 100 + w];
            *reinterpret_cast<ushort4*>(x2 + (((size_t)(b * HH + h) * WW + w) * CIN + c)) = u;
        }
    } else {
        const int o = blk - NWG;
        if (o == 0 && tid < 8) zbuf[tid] = 0;        // 16B zero source for pads
        if (tid < DD) wrow[tid] = 0.f;
        __syncthreads();
        if (tid == 0) {                              // deterministic serial scatter
            for (int s = 0; s < 27; ++s) wrow[idx[o * 27 + s]] += coeff[o * 27 + s];
        }
        __syncthreads();
        for (int j = tid; j < 576; j += 256) {       // j = kpos*64 + c
            int kpos = j >> 6, c = j & 63;
            float s = 0.f;
            for (int d = 0; d < DD; ++d)
                s += wrow[d] * dict[d * 576 + c * 9 + kpos];
            int otile = o >> 4, ks = c >> 5;
            int lane8 = (o & 15) | (((c >> 3) & 3) << 4);
            weff2[((size_t)(kpos * 32 + otile * 2 + ks)) * 512 + lane8 * 8 + (c & 7)]
                = f32_to_bf16(s);
        }
    }
}

// ---- conv: block = (b, row-pair h0..h0+1, w-half 48, ALL 256 o).
// 256 threads = 4 waves, each n=4 o-tiles; per wave q=2 x m=3 x n=4 = 24 MFMA/step.
// vs R16: A-LDS traffic halves (A-frag feeds 8 MFMAs), B-L2 unchanged, denser
// MFMA clusters cover the ping-pong's LDS latency. Regs ~235 at
// __launch_bounds__(256,2) (~256 cap, 2 blocks/CU).
__global__ __launch_bounds__(256, 2) void conv_kernel(
    const unsigned short* __restrict__ x2,     // [16][96][96][64] bf16 NHWC
    const unsigned short* __restrict__ weff2,  // fragment-ordered, 288KB (L2-resident)
    const unsigned short* __restrict__ zbuf,   // 16B of zeros
    float* __restrict__ out)                   // [16][256][96][96] f32
{
    __shared__ unsigned short xs[4 * WPAD * 64]; // 4 rows x 50 wp x 64c, 25600 B

    const int wg  = blockIdx.x;
    const int swz = (wg & 7) * (NCV / 8) + (wg >> 3);  // XCD-bijective (1536%8==0)
    const int b = swz / 96, rem = swz % 96;
    const int hp = rem >> 1, wh = rem & 1;             // wh fastest: L2 row sharing
    const int h0 = hp * 2, ws = wh * 48;
    const int tid = threadIdx.x;
    const int lane = tid & 63, wn = tid >> 6;          // wn = o-quarter (4 otiles each)
    const int l15 = lane & 15;

    char* xsb = reinterpret_cast<char*>(xs);
    const char* x2b = reinterpret_cast<const char*>(x2) + (size_t)b * HH * WW * 128;
    const char* zbp = reinterpret_cast<const char*>(zbuf);

    // ---- B-fragment prologue: banks for steps 0..3 (fly under staging) ----
    // otile(n) = wn*4 + n; frag = kpos*32 + otile*2 + ks
    const unsigned short* wbase = weff2 + (size_t)(wn * 8) * 512 + lane * 8;
    bf16x8 bfr[4][4];
#pragma unroll
    for (int s = 0; s < 4; ++s) {
        const int off = (s >> 1) * 32 + (s & 1);
#pragma unroll
        for (int n = 0; n < 4; ++n)
            bfr[s][n] = *reinterpret_cast<const bf16x8*>(wbase + (off + n * 2) * 512);
    }

    // ---- stage rows h0-1..h0+2, wp in [0,50) (global w = ws-1+wp) ----
#pragma unroll
    for (int it = 0; it < 7; ++it) {
        int chunk = tid + it * 256;            // 4*50*8 = 1600 chunks of 16B
        if (chunk < 1600) {
            int r = chunk / 400, rem2 = chunk % 400;
            int wp = rem2 >> 3, gb = (rem2 & 7) << 4;
            int hx = h0 - 1 + r, w = ws - 1 + wp;
            const char* src = (w >= 0 && w < WW && hx >= 0 && hx < HH)
                ? x2b + ((size_t)(hx * WW + w) * 128 + (gb ^ FSWZ(wp)))
                : zbp;
            __builtin_amdgcn_global_load_lds(
                (const __attribute__((address_space(1))) void*)src,
                (__attribute__((address_space(3))) void*)(xsb + chunk * 16),
                16, 0, 0);
        }
    }

    f32x4 acc[2][3][4];
#pragma unroll
    for (int q = 0; q < 2; ++q)
#pragma unroll
        for (int m = 0; m < 3; ++m)
#pragma unroll
            for (int n = 0; n < 4; ++n)
                acc[q][m][n] = (f32x4){0.f, 0.f, 0.f, 0.f};

    __syncthreads();                           // xs staged (only barrier)

    // ---- A ping-pong: preload step 0 (kh=0, dw=0, ks=0) for both rows ----
    bf16x8 ax[2][2][3];
    {
        const int cb0 = ((lane >> 4) * 8) * 2;
#pragma unroll
        for (int q = 0; q < 2; ++q)
#pragma unroll
            for (int m = 0; m < 3; ++m) {
                int wpos = m * 16 + l15;
                ax[0][q][m] = *reinterpret_cast<const bf16x8*>(
                    xsb + q * 6400 + wpos * 128 + (cb0 ^ FSWZ(wpos)));
            }
    }

    // ---- 18 half-steps: s = (kpos=s>>1, ks=s&1); bank = s&3, B-prefetch +4 ----
#pragma unroll
    for (int s = 0; s < 18; ++s) {
        if (s < 17) {                          // prefetch A for step s+1 (both rows)
            const int s1 = s + 1;
            const int kpos1 = s1 >> 1, ks1 = s1 & 1;
            const int kh1 = kpos1 / 3, dw1 = kpos1 % 3;
            const int cb1 = (ks1 * 32 + (lane >> 4) * 8) * 2;
#pragma unroll
            for (int q = 0; q < 2; ++q)
#pragma unroll
                for (int m = 0; m < 3; ++m) {
                    int wpos = m * 16 + l15 + dw1;
                    ax[s1 & 1][q][m] = *reinterpret_cast<const bf16x8*>(
                        xsb + (kh1 + q) * 6400 + wpos * 128 + (cb1 ^ FSWZ(wpos)));
                }
        }
        __builtin_amdgcn_s_setprio(1);
#pragma unroll
        for (int q = 0; q < 2; ++q)
#pragma unroll
            for (int m = 0; m < 3; ++m)
#pragma unroll
                for (int n = 0; n < 4; ++n)
                    acc[q][m][n] = __builtin_amdgcn_mfma_f32_16x16x32_bf16(
                        ax[s & 1][q][m], bfr[s & 3][n], acc[q][m][n], 0, 0, 0);
        __builtin_amdgcn_s_setprio(0);
        if (s < 14) {                          // reload this bank with step s+4
            const int s4 = s + 4;
            const int off = (s4 >> 1) * 32 + (s4 & 1);
#pragma unroll
            for (int n = 0; n < 4; ++n)
                bfr[s & 3][n] = *reinterpret_cast<const bf16x8*>(
                    wbase + (off + n * 2) * 512);
        }
    }

    // ---- epilogue: plain float4 stores ----
#pragma unroll
    for (int q = 0; q < 2; ++q)
#pragma unroll
        for (int m = 0; m < 3; ++m)
#pragma unroll
            for (int n = 0; n < 4; ++n) {
                int o = wn * 64 + n * 16 + l15;
                int w = ws + m * 16 + (lane >> 4) * 4;
                *reinterpret_cast<f32x4*>(
                    out + (((size_t)(b * OO + o) * HH + h0 + q) * WW + w))
                    = acc[q][m][n];
            }
}

extern "C" void kernel_launch(void* const* d_in, const int* in_sizes, int n_in,
                              void* d_out, int out_size, void* d_ws, size_t ws_size,
                              hipStream_t stream) {
    const float* x     = (const float*)d_in[0];
    const float* dict  = (const float*)d_in[1];
    const float* coeff = (const float*)d_in[2];
    const int*   idx   = (const int*)d_in[3];
    float* out = (float*)d_out;

    char* ws = (char*)d_ws;
    unsigned short* weff2 = (unsigned short*)ws;               // 294912 B
    unsigned short* zbuf  = (unsigned short*)(ws + 294912);    // 16 B zeros
    unsigned short* x2    = (unsigned short*)(ws + 1048576);   // 18874368 B

    prep_kernel<<<NWG + OO, 256, 0, stream>>>(x, dict, coeff, idx, x2, weff2, zbuf);
    conv_kernel<<<NCV, 256, 0, stream>>>(x2, weff2, zbuf, out);
}